// Round 2
// baseline (5739.875 us; speedup 1.0000x reference)
//
#include <hip/hip_runtime.h>
#include <hip/hip_fp16.h>
#include <cstdint>
#include <cstddef>

#define TT 512
#define BB 64
#define EE 256
#define HH 256
#define G4 1024   // 4*H
#define DD 512    // 2*H
#define NCLS 5
#define CH 32     // time-steps per chunk
#define NCH (TT / CH)

// Workspace layout (bytes). Total = 52,953,088 B (~50.5 MB).
#define OFF_XGF   0ull                 // 8,388,608  f32 [CH][64][1024]
#define OFF_XGB   8388608ull           // 8,388,608
#define OFF_OUTB  16777216ull          // 33,554,432 fp16 [512][64][512]
#define OFF_WPF   50331648ull          // 1,048,576  f32 [256][1024]
#define OFF_WPB   51380224ull          // 1,048,576
#define OFF_HST   52428800ull          // 131,072    f32 [2][64][256]
#define OFF_CST   52559872ull          // 131,072
#define OFF_LOG   52690944ull          // 131,072    f32 [512][64]
#define OFF_ATT   52822016ull          // 131,072

// ---------------------------------------------------------------------------
// Wp[k][4*j+q] = Whh[q*256 + j][k]  (per dir) -> one float4/lane/k in the scan
// ---------------------------------------------------------------------------
__global__ void make_wp(const float* __restrict__ WhhF, const float* __restrict__ WhhB,
                        float* __restrict__ WpF, float* __restrict__ WpB) {
  const float* W = blockIdx.y ? WhhB : WhhF;
  float* Wp = blockIdx.y ? WpB : WpF;
  int o = blockIdx.x * 256 + threadIdx.x;      // 0 .. 262143
  int k = o >> 10, col = o & 1023;
  int jj = col >> 2, q = col & 3;
  Wp[o] = W[(size_t)(q * HH + jj) * HH + k];
}

// ---------------------------------------------------------------------------
// xg chunk: for local step ls (=blockIdx.x) of chunk c, global t (dir-dep),
// xg_ch[dir][ls][b][g] = emb[idx[t,b]] . Wih[g] + bih[g] + bhh[g]
// Tile: 64 batch rows x 64 gate cols, 256 threads, f32.
// ---------------------------------------------------------------------------
__global__ __launch_bounds__(256) void xg_gemm_chunk(
    int c, const int* __restrict__ embed, const float* __restrict__ emb,
    const float* __restrict__ WihF, const float* __restrict__ WihB,
    const float* __restrict__ bihF, const float* __restrict__ bhhF,
    const float* __restrict__ bihB, const float* __restrict__ bhhB,
    float* __restrict__ xgF, float* __restrict__ xgB)
{
  const int dir = blockIdx.z;
  const float* Wih = dir ? WihB : WihF;
  const float* bih = dir ? bihB : bihF;
  const float* bhh = dir ? bhhB : bhhF;
  float* xg = dir ? xgB : xgF;
  const int ls = blockIdx.x;                   // 0..CH-1
  int t = c * CH + ls;
  if (dir) t = TT - 1 - t;
  const int g0 = blockIdx.y * 64;
  const int tid = threadIdx.x;

  __shared__ int idx[64];
  __shared__ float As[16][68];
  __shared__ float Bs[16][68];

  if (tid < 64) idx[tid] = embed[t * BB + tid];
  __syncthreads();

  const int tm = tid >> 4, tn = tid & 15;
  const int lm = tid >> 2, lk = (tid & 3) * 4;
  float acc[4][4] = {};

  for (int k0 = 0; k0 < EE; k0 += 16) {
    float4 av = *(const float4*)&emb[(size_t)idx[lm] * EE + k0 + lk];
    float4 bv = *(const float4*)&Wih[(size_t)(g0 + lm) * EE + k0 + lk];
    __syncthreads();
    As[lk + 0][lm] = av.x; As[lk + 1][lm] = av.y; As[lk + 2][lm] = av.z; As[lk + 3][lm] = av.w;
    Bs[lk + 0][lm] = bv.x; Bs[lk + 1][lm] = bv.y; Bs[lk + 2][lm] = bv.z; Bs[lk + 3][lm] = bv.w;
    __syncthreads();
#pragma unroll
    for (int k = 0; k < 16; ++k) {
      float4 a = *(const float4*)&As[k][tm * 4];
      float4 b = *(const float4*)&Bs[k][tn * 4];
      acc[0][0] += a.x * b.x; acc[0][1] += a.x * b.y; acc[0][2] += a.x * b.z; acc[0][3] += a.x * b.w;
      acc[1][0] += a.y * b.x; acc[1][1] += a.y * b.y; acc[1][2] += a.y * b.z; acc[1][3] += a.y * b.w;
      acc[2][0] += a.z * b.x; acc[2][1] += a.z * b.y; acc[2][2] += a.z * b.z; acc[2][3] += a.z * b.w;
      acc[3][0] += a.w * b.x; acc[3][1] += a.w * b.y; acc[3][2] += a.w * b.z; acc[3][3] += a.w * b.w;
    }
  }
  const int gc = g0 + tn * 4;
  const float bs0 = bih[gc + 0] + bhh[gc + 0];
  const float bs1 = bih[gc + 1] + bhh[gc + 1];
  const float bs2 = bih[gc + 2] + bhh[gc + 2];
  const float bs3 = bih[gc + 3] + bhh[gc + 3];
#pragma unroll
  for (int i = 0; i < 4; ++i) {
    float4 st;
    st.x = acc[i][0] + bs0; st.y = acc[i][1] + bs1;
    st.z = acc[i][2] + bs2; st.w = acc[i][3] + bs3;
    *(float4*)&xg[(size_t)(ls * 64 + tm * 4 + i) * G4 + gc] = st;
  }
}

// ---------------------------------------------------------------------------
// LSTM scan over one chunk of CH steps. grid (32,2): x = batch pair, y = dir.
// Thread j owns hidden unit j (4 gates via Wp permutation); c in regs, h in
// LDS double buffer. State carried across chunks via hstate/cstate.
// ---------------------------------------------------------------------------
__global__ __launch_bounds__(256) void scan_chunk(
    int c, const float* __restrict__ xgF, const float* __restrict__ xgB,
    const float* __restrict__ WpF, const float* __restrict__ WpB,
    const float* __restrict__ hin, const float* __restrict__ cin,
    float* __restrict__ hstate, float* __restrict__ cstate,
    __half* __restrict__ outb)
{
  const int dir = blockIdx.y;
  const int b0 = blockIdx.x * 2;
  const int j = threadIdx.x;
  const float* xg = dir ? xgB : xgF;
  const float* Wp = dir ? WpB : WpF;

  __shared__ float hbuf[2][2][HH];

  float cc[2];
#pragma unroll
  for (int r = 0; r < 2; ++r) {
    cc[r] = cin[(size_t)(dir * BB + b0 + r) * HH + j];
    hbuf[0][r][j] = hin[(size_t)(dir * BB + b0 + r) * HH + j];
  }
  __syncthreads();

  int buf = 0;
  for (int ls = 0; ls < CH; ++ls) {
    int t = c * CH + ls;
    if (dir) t = TT - 1 - t;
    float acc[4][2];
#pragma unroll
    for (int q = 0; q < 4; ++q)
#pragma unroll
      for (int r = 0; r < 2; ++r)
        acc[q][r] = xg[((size_t)(ls * 64) + b0 + r) * G4 + q * HH + j];

#pragma unroll 4
    for (int k = 0; k < HH; k += 4) {
      float4 hk0 = *(const float4*)&hbuf[buf][0][k];
      float4 hk1 = *(const float4*)&hbuf[buf][1][k];
      const float h0v[4] = {hk0.x, hk0.y, hk0.z, hk0.w};
      const float h1v[4] = {hk1.x, hk1.y, hk1.z, hk1.w};
#pragma unroll
      for (int kk = 0; kk < 4; ++kk) {
        float4 w = *(const float4*)&Wp[(size_t)(k + kk) * G4 + 4 * j];
        acc[0][0] += w.x * h0v[kk]; acc[0][1] += w.x * h1v[kk];
        acc[1][0] += w.y * h0v[kk]; acc[1][1] += w.y * h1v[kk];
        acc[2][0] += w.z * h0v[kk]; acc[2][1] += w.z * h1v[kk];
        acc[3][0] += w.w * h0v[kk]; acc[3][1] += w.w * h1v[kk];
      }
    }
#pragma unroll
    for (int r = 0; r < 2; ++r) {
      float ig = 1.f / (1.f + expf(-acc[0][r]));
      float fg = 1.f / (1.f + expf(-acc[1][r]));
      float gg = tanhf(acc[2][r]);
      float og = 1.f / (1.f + expf(-acc[3][r]));
      cc[r] = fg * cc[r] + ig * gg;
      float h = og * tanhf(cc[r]);
      hbuf[buf ^ 1][r][j] = h;
      outb[((size_t)t * BB + b0 + r) * DD + dir * HH + j] = __float2half(h);
    }
    __syncthreads();
    buf ^= 1;
  }
#pragma unroll
  for (int r = 0; r < 2; ++r) {
    hstate[(size_t)(dir * BB + b0 + r) * HH + j] = hbuf[buf][r][j];
    cstate[(size_t)(dir * BB + b0 + r) * HH + j] = cc[r];
  }
}

// ---------------------------------------------------------------------------
// logits[r] = sum_e tanh( (out[r,:] @ W_word)[e] + b_word[e] ) * proj[e]
// One block owns 64 rows x all 512 cols -> no atomics, deterministic.
// ---------------------------------------------------------------------------
__global__ __launch_bounds__(1024, 1) void squish_logits(
    const __half* __restrict__ outb, const float* __restrict__ Ww,
    const float* __restrict__ bw, const float* __restrict__ proj,
    float* __restrict__ logits)
{
  const int r0 = blockIdx.x * 64;
  const int tid = threadIdx.x;
  const int tm = tid >> 6;        // 0..15
  const int tn = tid & 63;        // 0..63
  __shared__ float As[16][68];
  __shared__ float Bs[16][516];
  __shared__ float red[64][65];

  float acc[4][8] = {};
  const int am = tid >> 4, ak = tid & 15;
  const int bk = tid >> 7, bn = (tid & 127) * 4;

  for (int k0 = 0; k0 < DD; k0 += 16) {
    float a0 = __half2float(outb[(size_t)(r0 + am) * DD + k0 + ak]);
    float4 b0 = *(const float4*)&Ww[(size_t)(k0 + bk) * DD + bn];
    float4 b1 = *(const float4*)&Ww[(size_t)(k0 + bk + 8) * DD + bn];
    __syncthreads();
    As[ak][am] = a0;
    *(float4*)&Bs[bk][bn] = b0;
    *(float4*)&Bs[bk + 8][bn] = b1;
    __syncthreads();
#pragma unroll
    for (int k = 0; k < 16; ++k) {
      float4 a = *(const float4*)&As[k][tm * 4];
      float4 p0 = *(const float4*)&Bs[k][tn * 8];
      float4 p1 = *(const float4*)&Bs[k][tn * 8 + 4];
      float av[4] = {a.x, a.y, a.z, a.w};
#pragma unroll
      for (int i = 0; i < 4; ++i) {
        acc[i][0] += av[i] * p0.x; acc[i][1] += av[i] * p0.y;
        acc[i][2] += av[i] * p0.z; acc[i][3] += av[i] * p0.w;
        acc[i][4] += av[i] * p1.x; acc[i][5] += av[i] * p1.y;
        acc[i][6] += av[i] * p1.z; acc[i][7] += av[i] * p1.w;
      }
    }
  }
  float partial[4] = {0.f, 0.f, 0.f, 0.f};
#pragma unroll
  for (int jj = 0; jj < 8; ++jj) {
    int col = tn * 8 + jj;
    float bwv = bw[col], pv = proj[col];
#pragma unroll
    for (int i = 0; i < 4; ++i)
      partial[i] += tanhf(acc[i][jj] + bwv) * pv;
  }
#pragma unroll
  for (int i = 0; i < 4; ++i) red[tm * 4 + i][tn] = partial[i];
  __syncthreads();
  if (tid < 64) {
    float s = 0.f;
    for (int x = 0; x < 64; ++x) s += red[tid][x];
    logits[r0 + tid] = s;
  }
}

// ---------------------------------------------------------------------------
// softmax over T (axis 0) for each b.  logits layout [t*64+b].
// ---------------------------------------------------------------------------
__global__ __launch_bounds__(256) void softmax_t(const float* __restrict__ logits,
                                                 float* __restrict__ attn)
{
  const int b = blockIdx.x;
  const int tid = threadIdx.x;
  __shared__ float sm[256];
  float v0 = logits[tid * BB + b];
  float v1 = logits[(tid + 256) * BB + b];
  sm[tid] = fmaxf(v0, v1);
  __syncthreads();
  for (int s = 128; s > 0; s >>= 1) {
    if (tid < s) sm[tid] = fmaxf(sm[tid], sm[tid + s]);
    __syncthreads();
  }
  float M = sm[0];
  __syncthreads();
  float e0 = expf(v0 - M), e1 = expf(v1 - M);
  sm[tid] = e0 + e1;
  __syncthreads();
  for (int s = 128; s > 0; s >>= 1) {
    if (tid < s) sm[tid] += sm[tid + s];
    __syncthreads();
  }
  float inv = 1.f / sm[0];
  attn[tid * BB + b] = e0 * inv;
  attn[(tid + 256) * BB + b] = e1 * inv;
}

// ---------------------------------------------------------------------------
// vec[b] = sum_t attn[t,b]*out[t,b,:]; y[b] = vec @ lin_W^T + lin_b
// ---------------------------------------------------------------------------
__global__ __launch_bounds__(512) void vec_final(
    const __half* __restrict__ outb, const float* __restrict__ attn,
    const float* __restrict__ linW, const float* __restrict__ linb,
    float* __restrict__ y)
{
  const int b = blockIdx.x;
  const int d = threadIdx.x;
  float acc = 0.f;
  for (int t = 0; t < TT; ++t)
    acc += attn[t * BB + b] * __half2float(outb[((size_t)t * BB + b) * DD + d]);
  __shared__ float red[512];
  for (int cls = 0; cls < NCLS; ++cls) {
    red[d] = acc * linW[cls * DD + d];
    __syncthreads();
    for (int s = 256; s > 0; s >>= 1) {
      if (d < s) red[d] += red[d + s];
      __syncthreads();
    }
    if (d == 0) y[b * NCLS + cls] = red[0] + linb[cls];
    __syncthreads();
  }
}

// ---------------------------------------------------------------------------
extern "C" void kernel_launch(void* const* d_in, const int* in_sizes, int n_in,
                              void* d_out, int out_size, void* d_ws, size_t ws_size,
                              hipStream_t stream) {
  const int*   embed     = (const int*)d_in[0];
  const float* h0        = (const float*)d_in[1];
  const float* c0        = (const float*)d_in[2];
  const float* emb_table = (const float*)d_in[3];
  const float* Wih_f     = (const float*)d_in[4];
  const float* Whh_f     = (const float*)d_in[5];
  const float* bih_f     = (const float*)d_in[6];
  const float* bhh_f     = (const float*)d_in[7];
  const float* Wih_b     = (const float*)d_in[8];
  const float* Whh_b     = (const float*)d_in[9];
  const float* bih_b     = (const float*)d_in[10];
  const float* bhh_b     = (const float*)d_in[11];
  const float* W_word    = (const float*)d_in[12];
  const float* b_word    = (const float*)d_in[13];
  const float* proj_word = (const float*)d_in[14];
  const float* lin_W     = (const float*)d_in[15];
  const float* lin_b     = (const float*)d_in[16];

  char* ws = (char*)d_ws;
  float*  xgF    = (float*)(ws + OFF_XGF);
  float*  xgB    = (float*)(ws + OFF_XGB);
  __half* outb   = (__half*)(ws + OFF_OUTB);
  float*  WpF    = (float*)(ws + OFF_WPF);
  float*  WpB    = (float*)(ws + OFF_WPB);
  float*  hstate = (float*)(ws + OFF_HST);
  float*  cstate = (float*)(ws + OFF_CST);
  float*  logits = (float*)(ws + OFF_LOG);
  float*  attn   = (float*)(ws + OFF_ATT);

  make_wp<<<dim3(1024, 2), 256, 0, stream>>>(Whh_f, Whh_b, WpF, WpB);

  for (int c = 0; c < NCH; ++c) {
    xg_gemm_chunk<<<dim3(CH, 16, 2), 256, 0, stream>>>(c, embed, emb_table,
        Wih_f, Wih_b, bih_f, bhh_f, bih_b, bhh_b, xgF, xgB);
    const float* hin = (c == 0) ? h0 : hstate;
    const float* cin = (c == 0) ? c0 : cstate;
    scan_chunk<<<dim3(32, 2), 256, 0, stream>>>(c, xgF, xgB, WpF, WpB,
        hin, cin, hstate, cstate, outb);
  }

  squish_logits<<<512, 1024, 0, stream>>>(outb, W_word, b_word, proj_word, logits);
  softmax_t<<<64, 256, 0, stream>>>(logits, attn);
  vec_final<<<64, 512, 0, stream>>>(outb, attn, lin_W, lin_b, (float*)d_out);
}

// Round 3
// 4701.988 us; speedup vs baseline: 1.2207x; 1.2207x over previous
//
#include <hip/hip_runtime.h>
#include <hip/hip_fp16.h>
#include <cstdint>
#include <cstddef>

#define TT 512
#define BB 64
#define EE 256
#define HH 256
#define G4 1024   // 4*H
#define DD 512    // 2*H
#define NCLS 5
#define CH 64     // time-steps per chunk
#define NCH (TT / CH)

typedef _Float16 half8 __attribute__((ext_vector_type(8)));
typedef float f32x4 __attribute__((ext_vector_type(4)));

// Workspace layout (bytes). Total = 52,961,280 B (~50.5 MB, matches known-good).
#define OFF_XGF   0ull                 // 8,388,608  fp16 [CH][64][1024]
#define OFF_XGB   8388608ull           // 8,388,608
#define OFF_OUTB  16777216ull          // 33,554,432 fp16 [512][64][512]
#define OFF_WHHF  50331648ull          // 1,048,576  fp16 frag [2][16][4][8][64][8]
#define OFF_WIHF  51380224ull          // 1,048,576  fp16 frag [2][64][8][64][8]
#define OFF_BIAS  52428800ull          // 8,192      f32 [2][1024]
#define OFF_HST   52436992ull          // 131,072    f32 [2][64][256]
#define OFF_CST   52568064ull          // 131,072
#define OFF_LOG   52699136ull          // 131,072    f32 [512][64]
#define OFF_ATT   52830208ull          // 131,072

__device__ __forceinline__ f32x4 mfma16(half8 a, half8 b, f32x4 c) {
  return __builtin_amdgcn_mfma_f32_16x16x32_f16(a, b, c, 0, 0, 0);
}
__device__ __forceinline__ float sigm(float x) {
  return __fdividef(1.f, 1.f + __expf(-x));
}
__device__ __forceinline__ float tanh_(float x) {
  float e = __expf(2.f * x);
  return 1.f - __fdividef(2.f, e + 1.f);
}

// ---------------------------------------------------------------------------
// Fragment-order the weights (fp16).
// Whhfrag[d][w][q][ks][lane][r] = Whh_d[q*256 + w*16 + (lane&15)][ks*32 + (lane>>4)*8 + r]
// Wihfrag[d][g16][ks][lane][r]  = Wih_d[g16*16 + (lane&15)][ks*32 + (lane>>4)*8 + r]
// ---------------------------------------------------------------------------
__global__ __launch_bounds__(256) void make_frags(
    const float* __restrict__ WhhF, const float* __restrict__ WhhB,
    const float* __restrict__ WihF, const float* __restrict__ WihB,
    __half* __restrict__ whhfrag, __half* __restrict__ wihfrag)
{
  int idx = blockIdx.x * 256 + threadIdx.x;   // 0 .. 2^20-1
  int r = idx & 7, lane = (idx >> 3) & 63, ks = (idx >> 9) & 7;
  int k = ks * 32 + (lane >> 4) * 8 + r;
  if (idx < (1 << 19)) {
    int q = (idx >> 12) & 3, w = (idx >> 14) & 15, d = (idx >> 18) & 1;
    const float* W = d ? WhhB : WhhF;
    int g = q * 256 + w * 16 + (lane & 15);
    whhfrag[idx] = __float2half(W[(size_t)g * HH + k]);
  } else {
    int e = idx - (1 << 19);
    int g16 = (e >> 12) & 63, d = (e >> 18) & 1;
    const float* W = d ? WihB : WihF;
    int g = g16 * 16 + (lane & 15);
    wihfrag[e] = __float2half(W[(size_t)g * EE + k]);
  }
}

__global__ __launch_bounds__(256) void bias_prep(
    const float* __restrict__ bihF, const float* __restrict__ bhhF,
    const float* __restrict__ bihB, const float* __restrict__ bhhB,
    float* __restrict__ bias)
{
  int i = blockIdx.x * 256 + threadIdx.x;    // 0..2047
  int d = i >> 10, g = i & 1023;
  bias[i] = (d ? bihB : bihF)[g] + (d ? bhhB : bhhF)[g];
}

// ---------------------------------------------------------------------------
// xg chunk via MFMA: xg[ls][b][g] = x[b]·Wih[g] + bias[g]  (fp16 in, f32 acc,
// fp16 out). Block: one t-step (64 batch rows) x 64 gate cols, 4 waves.
// ---------------------------------------------------------------------------
__global__ __launch_bounds__(256) void xg_mfma(
    int c, const int* __restrict__ embed, const float* __restrict__ emb,
    const __half* __restrict__ wihfrag, const float* __restrict__ biassum,
    __half* __restrict__ xgF, __half* __restrict__ xgB)
{
  const int d = blockIdx.z, ls = blockIdx.x, gblk = blockIdx.y;
  int t = c * CH + ls;
  if (d) t = TT - 1 - t;
  __half* xg = d ? xgB : xgF;
  const int tid = threadIdx.x, w = tid >> 6, l = tid & 63;

  __shared__ int idx[64];
  __shared__ unsigned short xs[64 * 256];   // 32 KB, swizzled fp16 x

  if (tid < 64) idx[tid] = embed[t * BB + tid];
  __syncthreads();

  // stage x: thread owns row rr, 64-col quarter cq
  {
    const int rr = tid >> 2, cq = (tid & 3) * 64;
    const float* src = emb + (size_t)idx[rr] * EE + cq;
#pragma unroll
    for (int j = 0; j < 8; ++j) {
      float4 a = *(const float4*)(src + j * 8);
      float4 b = *(const float4*)(src + j * 8 + 4);
      half8 hv;
      hv[0] = (_Float16)a.x; hv[1] = (_Float16)a.y; hv[2] = (_Float16)a.z; hv[3] = (_Float16)a.w;
      hv[4] = (_Float16)b.x; hv[5] = (_Float16)b.y; hv[6] = (_Float16)b.z; hv[7] = (_Float16)b.w;
      int hidx = (rr * 256 + cq + j * 8) ^ ((rr & 7) << 3);
      *(half8*)&xs[hidx] = hv;
    }
  }
  __syncthreads();

  // B fragments (L2-resident, frag-ordered)
  const __half* bfb = wihfrag + (size_t)((d * 64 + gblk * 4) * 8) * 512 + l * 8;
  half8 Bf[4][8];
#pragma unroll
  for (int ct = 0; ct < 4; ++ct)
#pragma unroll
    for (int ks = 0; ks < 8; ++ks)
      Bf[ct][ks] = *(const half8*)(bfb + (ct * 8 + ks) * 512);

  f32x4 acc[4];
#pragma unroll
  for (int ct = 0; ct < 4; ++ct) {
    float bv = biassum[d * 1024 + gblk * 64 + ct * 16 + (l & 15)];
    acc[ct][0] = bv; acc[ct][1] = bv; acc[ct][2] = bv; acc[ct][3] = bv;
  }

  const int arow = w * 16 + (l & 15);
#pragma unroll
  for (int ks = 0; ks < 8; ++ks) {
    int hidx = (arow * 256 + ks * 32 + (l >> 4) * 8) ^ ((arow & 7) << 3);
    half8 af = *(const half8*)&xs[hidx];
#pragma unroll
    for (int ct = 0; ct < 4; ++ct)
      acc[ct] = mfma16(af, Bf[ct][ks], acc[ct]);
  }

#pragma unroll
  for (int ct = 0; ct < 4; ++ct)
#pragma unroll
    for (int r = 0; r < 4; ++r) {
      int b = w * 16 + (l >> 4) * 4 + r;
      int g = gblk * 64 + ct * 16 + (l & 15);
      xg[((size_t)ls * 64 + b) * G4 + g] = __float2half(acc[ct][r]);
    }
}

// ---------------------------------------------------------------------------
// LSTM scan chunk via MFMA. grid (4,2): 16 batch rows x dir per block,
// 16 waves; wave w owns units [16w,16w+16) for all 4 gates (B-perm in frags).
// Whh frags in 128 VGPRs; h fp16 in swizzled LDS double buffer; c f32 regs.
// ---------------------------------------------------------------------------
__global__ __launch_bounds__(1024) void scan_mfma(
    int c, const __half* __restrict__ xgF, const __half* __restrict__ xgB,
    const __half* __restrict__ whhfrag,
    const float* __restrict__ hin, const float* __restrict__ cin,
    float* __restrict__ hstate, float* __restrict__ cstate,
    __half* __restrict__ outb)
{
  const int d = blockIdx.y, bx = blockIdx.x;
  const int tid = threadIdx.x, w = tid >> 6, l = tid & 63;
  const __half* xg = d ? xgB : xgF;

  __shared__ unsigned short hb[2][16 * 256];   // 2 x 8 KB, swizzled fp16 h

  // B fragments -> registers (held across the whole chunk)
  const __half* bfb = whhfrag + (size_t)((d * 16 + w) * 32) * 512 + l * 8;
  half8 Bf[4][8];
#pragma unroll
  for (int q = 0; q < 4; ++q)
#pragma unroll
    for (int ks = 0; ks < 8; ++ks)
      Bf[q][ks] = *(const half8*)(bfb + (q * 8 + ks) * 512);

  const int u = w * 16 + (l & 15);
  const int qr = l >> 4;
  float cst[4], hval[4];
#pragma unroll
  for (int r = 0; r < 4; ++r) {
    int br = qr * 4 + r;
    int gb = d * BB + bx * 16 + br;
    cst[r] = cin[(size_t)gb * HH + u];
    float hv = hin[(size_t)gb * HH + u];
    hval[r] = hv;
    hb[0][(br * 256 + u) ^ ((br & 7) << 3)] = __half_as_ushort(__float2half(hv));
  }
  __syncthreads();

  // xg base for this lane: rows (bx*16 + qr*4 + r), col q*256 + u
  const __half* xgbase = xg + (size_t)(bx * 16 + qr * 4) * G4 + u;

#define LOAD_XG(dst, lsv)                                                    \
  {                                                                          \
    _Pragma("unroll") for (int q_ = 0; q_ < 4; ++q_) {                       \
      _Pragma("unroll") for (int r_ = 0; r_ < 4; ++r_) {                     \
        dst[q_][r_] = __half2float(                                          \
            xgbase[(size_t)((lsv) * 64 + r_) * G4 + q_ * 256]);              \
      }                                                                      \
    }                                                                        \
  }

  float xgn[4][4];
  LOAD_XG(xgn, 0);

  int buf = 0;
  for (int ls = 0; ls < CH; ++ls) {
    int t = c * CH + ls;
    if (d) t = TT - 1 - t;

    // A fragments: h_prev for all units
    half8 af[8];
#pragma unroll
    for (int ks = 0; ks < 8; ++ks) {
      int hidx = ((l & 15) * 256 + ks * 32 + qr * 8) ^ (((l & 15) & 7) << 3);
      af[ks] = *(const half8*)&hb[buf][hidx];
    }

    // C-init from xg (already includes x@Wih^T + biases)
    f32x4 acc[4];
#pragma unroll
    for (int q = 0; q < 4; ++q) {
      acc[q][0] = xgn[q][0]; acc[q][1] = xgn[q][1];
      acc[q][2] = xgn[q][2]; acc[q][3] = xgn[q][3];
    }

    // prefetch next step's xg (overlaps MFMA + VALU)
    int lsn = (ls + 1 < CH) ? ls + 1 : ls;
    LOAD_XG(xgn, lsn);

#pragma unroll
    for (int ks = 0; ks < 8; ++ks)
#pragma unroll
      for (int q = 0; q < 4; ++q)
        acc[q] = mfma16(af[ks], Bf[q][ks], acc[q]);

#pragma unroll
    for (int r = 0; r < 4; ++r) {
      float ig = sigm(acc[0][r]);
      float fg = sigm(acc[1][r]);
      float gg = tanh_(acc[2][r]);
      float og = sigm(acc[3][r]);
      cst[r] = fg * cst[r] + ig * gg;
      float hv = og * tanh_(cst[r]);
      hval[r] = hv;
      int br = qr * 4 + r;
      unsigned short hu = __half_as_ushort(__float2half(hv));
      hb[buf ^ 1][(br * 256 + u) ^ ((br & 7) << 3)] = hu;
      outb[((size_t)t * BB + bx * 16 + br) * DD + d * HH + u] = __ushort_as_half(hu);
    }
    __syncthreads();
    buf ^= 1;
  }

#pragma unroll
  for (int r = 0; r < 4; ++r) {
    int gb = d * BB + bx * 16 + qr * 4 + r;
    hstate[(size_t)gb * HH + u] = hval[r];
    cstate[(size_t)gb * HH + u] = cst[r];
  }
#undef LOAD_XG
}

// ---------------------------------------------------------------------------
// logits[r] = sum_e tanh( (out[r,:] @ W_word)[e] + b_word[e] ) * proj[e]
// ---------------------------------------------------------------------------
__global__ __launch_bounds__(1024, 1) void squish_logits(
    const __half* __restrict__ outb, const float* __restrict__ Ww,
    const float* __restrict__ bw, const float* __restrict__ proj,
    float* __restrict__ logits)
{
  const int r0 = blockIdx.x * 64;
  const int tid = threadIdx.x;
  const int tm = tid >> 6;        // 0..15
  const int tn = tid & 63;        // 0..63
  __shared__ float As[16][68];
  __shared__ float Bs[16][516];
  __shared__ float red[64][65];

  float acc[4][8] = {};
  const int am = tid >> 4, ak = tid & 15;
  const int bk = tid >> 7, bn = (tid & 127) * 4;

  for (int k0 = 0; k0 < DD; k0 += 16) {
    float a0 = __half2float(outb[(size_t)(r0 + am) * DD + k0 + ak]);
    float4 b0 = *(const float4*)&Ww[(size_t)(k0 + bk) * DD + bn];
    float4 b1 = *(const float4*)&Ww[(size_t)(k0 + bk + 8) * DD + bn];
    __syncthreads();
    As[ak][am] = a0;
    *(float4*)&Bs[bk][bn] = b0;
    *(float4*)&Bs[bk + 8][bn] = b1;
    __syncthreads();
#pragma unroll
    for (int k = 0; k < 16; ++k) {
      float4 a = *(const float4*)&As[k][tm * 4];
      float4 p0 = *(const float4*)&Bs[k][tn * 8];
      float4 p1 = *(const float4*)&Bs[k][tn * 8 + 4];
      float av[4] = {a.x, a.y, a.z, a.w};
#pragma unroll
      for (int i = 0; i < 4; ++i) {
        acc[i][0] += av[i] * p0.x; acc[i][1] += av[i] * p0.y;
        acc[i][2] += av[i] * p0.z; acc[i][3] += av[i] * p0.w;
        acc[i][4] += av[i] * p1.x; acc[i][5] += av[i] * p1.y;
        acc[i][6] += av[i] * p1.z; acc[i][7] += av[i] * p1.w;
      }
    }
  }
  float partial[4] = {0.f, 0.f, 0.f, 0.f};
#pragma unroll
  for (int jj = 0; jj < 8; ++jj) {
    int col = tn * 8 + jj;
    float bwv = bw[col], pv = proj[col];
#pragma unroll
    for (int i = 0; i < 4; ++i)
      partial[i] += tanhf(acc[i][jj] + bwv) * pv;
  }
#pragma unroll
  for (int i = 0; i < 4; ++i) red[tm * 4 + i][tn] = partial[i];
  __syncthreads();
  if (tid < 64) {
    float s = 0.f;
    for (int x = 0; x < 64; ++x) s += red[tid][x];
    logits[r0 + tid] = s;
  }
}

// ---------------------------------------------------------------------------
__global__ __launch_bounds__(256) void softmax_t(const float* __restrict__ logits,
                                                 float* __restrict__ attn)
{
  const int b = blockIdx.x;
  const int tid = threadIdx.x;
  __shared__ float sm[256];
  float v0 = logits[tid * BB + b];
  float v1 = logits[(tid + 256) * BB + b];
  sm[tid] = fmaxf(v0, v1);
  __syncthreads();
  for (int s = 128; s > 0; s >>= 1) {
    if (tid < s) sm[tid] = fmaxf(sm[tid], sm[tid + s]);
    __syncthreads();
  }
  float M = sm[0];
  __syncthreads();
  float e0 = expf(v0 - M), e1 = expf(v1 - M);
  sm[tid] = e0 + e1;
  __syncthreads();
  for (int s = 128; s > 0; s >>= 1) {
    if (tid < s) sm[tid] += sm[tid + s];
    __syncthreads();
  }
  float inv = 1.f / sm[0];
  attn[tid * BB + b] = e0 * inv;
  attn[(tid + 256) * BB + b] = e1 * inv;
}

// ---------------------------------------------------------------------------
__global__ __launch_bounds__(512) void vec_final(
    const __half* __restrict__ outb, const float* __restrict__ attn,
    const float* __restrict__ linW, const float* __restrict__ linb,
    float* __restrict__ y)
{
  const int b = blockIdx.x;
  const int d = threadIdx.x;
  float acc = 0.f;
  for (int t = 0; t < TT; ++t)
    acc += attn[t * BB + b] * __half2float(outb[((size_t)t * BB + b) * DD + d]);
  __shared__ float red[512];
  for (int cls = 0; cls < NCLS; ++cls) {
    red[d] = acc * linW[cls * DD + d];
    __syncthreads();
    for (int s = 256; s > 0; s >>= 1) {
      if (d < s) red[d] += red[d + s];
      __syncthreads();
    }
    if (d == 0) y[b * NCLS + cls] = red[0] + linb[cls];
    __syncthreads();
  }
}

// ---------------------------------------------------------------------------
extern "C" void kernel_launch(void* const* d_in, const int* in_sizes, int n_in,
                              void* d_out, int out_size, void* d_ws, size_t ws_size,
                              hipStream_t stream) {
  const int*   embed     = (const int*)d_in[0];
  const float* h0        = (const float*)d_in[1];
  const float* c0        = (const float*)d_in[2];
  const float* emb_table = (const float*)d_in[3];
  const float* Wih_f     = (const float*)d_in[4];
  const float* Whh_f     = (const float*)d_in[5];
  const float* bih_f     = (const float*)d_in[6];
  const float* bhh_f     = (const float*)d_in[7];
  const float* Wih_b     = (const float*)d_in[8];
  const float* Whh_b     = (const float*)d_in[9];
  const float* bih_b     = (const float*)d_in[10];
  const float* bhh_b     = (const float*)d_in[11];
  const float* W_word    = (const float*)d_in[12];
  const float* b_word    = (const float*)d_in[13];
  const float* proj_word = (const float*)d_in[14];
  const float* lin_W     = (const float*)d_in[15];
  const float* lin_b     = (const float*)d_in[16];

  char* ws = (char*)d_ws;
  __half* xgF     = (__half*)(ws + OFF_XGF);
  __half* xgB     = (__half*)(ws + OFF_XGB);
  __half* outb    = (__half*)(ws + OFF_OUTB);
  __half* whhfrag = (__half*)(ws + OFF_WHHF);
  __half* wihfrag = (__half*)(ws + OFF_WIHF);
  float*  biassum = (float*)(ws + OFF_BIAS);
  float*  hstate  = (float*)(ws + OFF_HST);
  float*  cstate  = (float*)(ws + OFF_CST);
  float*  logits  = (float*)(ws + OFF_LOG);
  float*  attn    = (float*)(ws + OFF_ATT);

  make_frags<<<4096, 256, 0, stream>>>(Whh_f, Whh_b, Wih_f, Wih_b, whhfrag, wihfrag);
  bias_prep<<<8, 256, 0, stream>>>(bih_f, bhh_f, bih_b, bhh_b, biassum);

  for (int c = 0; c < NCH; ++c) {
    xg_mfma<<<dim3(CH, 16, 2), 256, 0, stream>>>(c, embed, emb_table,
        wihfrag, biassum, xgF, xgB);
    const float* hin = (c == 0) ? h0 : hstate;
    const float* cin = (c == 0) ? c0 : cstate;
    scan_mfma<<<dim3(4, 2), 1024, 0, stream>>>(c, xgF, xgB, whhfrag,
        hin, cin, hstate, cstate, outb);
  }

  squish_logits<<<512, 1024, 0, stream>>>(outb, W_word, b_word, proj_word, logits);
  softmax_t<<<64, 256, 0, stream>>>(logits, attn);
  vec_final<<<64, 512, 0, stream>>>(outb, attn, lin_W, lin_b, (float*)d_out);
}